// Round 15
// baseline (219.638 us; speedup 1.0000x reference)
//
#include <hip/hip_runtime.h>

#define N_NODES  50000
#define N_EDGES  800000
#define HID      128
#define OUT_C    16
#define N_GRAPHS 128
#define MAXDEG   64     // r26: 32 didn't cut WRITE_SIZE; 64 is safe
#define NSLICE   6250   // N_NODES / 8; slice s owns [s*6250,(s+1)*6250)
#define EPB      2048   // r32: 8 edges/thread — probes atomic-MLP vs L2-atomic
                        // throughput bound (r29's 4-deep chains = 49.5us)
#define AGB      3125   // agg_gemm blocks
#define PAD      136    // +8 bf16 pad -> frag reads 2-way (free) not 16-way

// r22 mega layout (re-derived for EPB 2048): groups of 40 = 32 fill + 8 gemm;
// 40%8==0 and 32%8==0 so fi&7 == b&7 — slice<->XCD alignment preserved
// (r20: breaking it = +17.6MB writebacks) while gemm overlaps fill from t=0.
// ATOMIC LESSONS: r23 fp32 atomicAdd = CAS retry (+55us). r30 int64 atomic
// = native but ~16B HBM traffic/op (6.4M ops = +65us). r31 LDS-pre-reduced
// fusion = neutral (overhead offsets Hb savings) — keep Hb + pool_partial.
// r26: mega's excess WRITE = scattered-2B sector granularity, intrinsic.
// r27/r28: separable-norm regressed (agg is gather-latency-bound).
// r29: int4 single-wait fill loads 55.5->49.3us.
#define GRP      40
#define NGRP     97     // full groups: 3104 fill + 776 gemm
#define GB0      3880   // NGRP*GRP (%8==0); tail: 24 fill + 6 gemm + 1 bounds

typedef __attribute__((ext_vector_type(8))) short bf16x8;
typedef __attribute__((ext_vector_type(4))) float f32x4;
typedef __attribute__((ext_vector_type(4))) int i32x4;
typedef __attribute__((ext_vector_type(8))) unsigned short us8;
typedef __attribute__((ext_vector_type(4))) unsigned short us4;

__device__ __forceinline__ unsigned short f2bf(float f) {
  unsigned u = __float_as_uint(f);
  u += 0x7fffu + ((u >> 16) & 1u);   // RNE
  return (unsigned short)(u >> 16);
}

// ---------------- shared MFMA compute+store, 256-thread version -------------
// 16x16x32 MFMA; A: m=lane&15,k=quad*8+j (LDS); B: n=lane&15,k=quad*8+j
// loaded straight from global fp32 W[k][n] (L2-broadcast). C/D:
// col=lane&15,row=quad*4+reg.
// r18 lesson: NO nontemporal stores on T — gathered with ~16x reuse next.
__device__ __forceinline__ void gemm_compute_store(
    unsigned short* sA, const float* __restrict__ W,
    unsigned short* __restrict__ T, int base) {
  const int tid = threadIdx.x;
  const int lane = tid & 63;
  const int w = tid >> 6;
  const int l15 = lane & 15;
  const int quad = lane >> 4;
  __syncthreads();

  f32x4 acc[4][2];
#pragma unroll
  for (int nt = 0; nt < 4; ++nt)
#pragma unroll
    for (int c = 0; c < 2; ++c) acc[nt][c] = (f32x4)(0.f);

  const int ct0 = w * 2;
  const int ncol = ct0 * 16 + l15;
#pragma unroll
  for (int ks = 0; ks < 4; ++ks) {
    const int koff = ks * 32 + quad * 8;
    bf16x8 a[4], bfr[2];
#pragma unroll
    for (int c = 0; c < 2; ++c) {
      const float* wp = W + (size_t)koff * HID + ncol + c * 16;
#pragma unroll
      for (int j = 0; j < 8; ++j) bfr[c][j] = (short)f2bf(wp[(size_t)j * HID]);
    }
#pragma unroll
    for (int nt = 0; nt < 4; ++nt)
      a[nt] = *(const bf16x8*)(sA + (nt * 16 + l15) * PAD + koff);
#pragma unroll
    for (int nt = 0; nt < 4; ++nt)
#pragma unroll
      for (int c = 0; c < 2; ++c)
        acc[nt][c] = __builtin_amdgcn_mfma_f32_16x16x32_bf16(a[nt], bfr[c], acc[nt][c], 0, 0, 0);
  }
  __syncthreads();

#pragma unroll
  for (int nt = 0; nt < 4; ++nt)
#pragma unroll
    for (int c = 0; c < 2; ++c)
#pragma unroll
      for (int r = 0; r < 4; ++r)
        sA[(nt * 16 + quad * 4 + r) * PAD + (ct0 + c) * 16 + l15] = f2bf(acc[nt][c][r]);
  __syncthreads();
#pragma unroll
  for (int i = 0; i < 4; ++i) {
    int idx = tid + i * 256;
    int nrow = idx >> 4;
    int col = (idx & 15) * 8;
    int node = base + nrow;
    if (node < N_NODES)
      *(us8*)(T + (size_t)node * HID + col) = *(const us8*)(sA + nrow * PAD + col);
  }
}

// stage A from fp32 (convert to bf16): 64 rows x 32 float4 = 2048
// r22 (kept): NT loads — x is read-once streaming. ext-vector f32x4 required.
__device__ __forceinline__ void stage_a_f32(unsigned short* sA,
                                            const float* __restrict__ H, int base) {
#pragma unroll
  for (int i = 0; i < 8; ++i) {
    int idx = threadIdx.x + i * 256;
    int nrow = idx >> 5;
    int c4 = (idx & 31) * 4;
    f32x4 v = (f32x4)(0.f);
    int node = base + nrow;
    if (node < N_NODES)
      v = __builtin_nontemporal_load((const f32x4*)(H + (size_t)node * HID + c4));
    us4 b;
    b.x = f2bf(v.x); b.y = f2bf(v.y); b.z = f2bf(v.z); b.w = f2bf(v.w);
    *(us4*)(sA + nrow * PAD + c4) = b;
  }
}

// ---- mega: 97 groups of (32 fill + 8 gemm) + tail(24 fill + 6 gemm + bounds)
// r32: fill = 8 edges/thread, FOUR i32x4 NT loads issued up front (one vmcnt
// drain), then 8 INDEPENDENT atomic->store chains — probes whether fill is
// atomic-MLP-limited (r29 had 4 chains) or L2-atomic-throughput-limited.
__global__ __launch_bounds__(256) void mega_kernel(
    const int* __restrict__ src, const int* __restrict__ dst,
    int* __restrict__ deg, unsigned short* __restrict__ ell,
    const int* __restrict__ batch, int* __restrict__ start,
    const float* __restrict__ x, const float* __restrict__ W1,
    unsigned short* __restrict__ T) {
  __shared__ unsigned short sA[64 * PAD];   // 17.4 KB
  const int b = blockIdx.x;
  int fi = -1, gi = -1;
  if (b < GB0) {
    const int g = b / GRP, r = b % GRP;
    if (r < 32) fi = g * 32 + r;            // fi&7 == b&7 (32,40 both %8==0)
    else        gi = g * 8 + (r - 32);
  } else {
    const int r = b - GB0;                  // GB0%8==0 -> alignment kept
    if (r < 24)      fi = NGRP * 32 + r;
    else if (r < 30) gi = NGRP * 8 + (r - 24);
    // r==30 -> bounds
  }
  if (fi >= 0) {
    const int slice = fi & 7;
    const int e0 = (fi >> 3) * EPB;
    const unsigned lo = slice * NSLICE;
    if (e0 + EPB <= N_EDGES) {              // fast path: exactly 8 edges/thread
      const int eb = e0 + threadIdx.x * 8;
      i32x4 d4a = __builtin_nontemporal_load((const i32x4*)(dst + eb));
      i32x4 d4b = __builtin_nontemporal_load((const i32x4*)(dst + eb + 4));
      i32x4 s4a = __builtin_nontemporal_load((const i32x4*)(src + eb));
      i32x4 s4b = __builtin_nontemporal_load((const i32x4*)(src + eb + 4));
#pragma unroll
      for (int i = 0; i < 4; ++i) {
        int d = d4a[i];
        if ((unsigned)(d - lo) < (unsigned)NSLICE) {
          int p = atomicAdd(&deg[d], 1);
          if (p < MAXDEG) ell[(d << 6) + p] = (unsigned short)s4a[i];
        }
      }
#pragma unroll
      for (int i = 0; i < 4; ++i) {
        int d = d4b[i];
        if ((unsigned)(d - lo) < (unsigned)NSLICE) {
          int p = atomicAdd(&deg[d], 1);
          if (p < MAXDEG) ell[(d << 6) + p] = (unsigned short)s4b[i];
        }
      }
    } else {                                // tail chunk (1280 edges)
      for (int e = e0 + threadIdx.x; e < N_EDGES; e += 256) {
        int d = dst[e];
        if ((unsigned)(d - lo) < (unsigned)NSLICE) {
          int p = atomicAdd(&deg[d], 1);
          if (p < MAXDEG) ell[(d << 6) + p] = (unsigned short)src[e];
        }
      }
    }
  } else if (gi >= 0) {
    const int base = gi * 64;
    stage_a_f32(sA, x, base);
    gemm_compute_store(sA, W1, T, base);
  } else {
    int t = threadIdx.x;                       // graph bounds (batch sorted)
    if (t <= N_GRAPHS) {
      int lo = 0, hi = N_NODES;
      while (lo < hi) {
        int mid = (lo + hi) >> 1;
        if (batch[mid] < t) lo = mid + 1; else hi = mid;
      }
      start[t] = lo;
    }
  }
}

// ------- agg core, pass 1: gathers deg[src] (scattered, once) + PACKS -------
// lane owns 2 bf16 channels; coalesced ell load + scattered deg gather, then
// readlane-broadcast with 8 independent row gathers in flight. Packs
// (src | fp16(weight)<<16) into ellw so pass 2 never touches deg[].
// r20 (kept): padded-tail — lanes >= m hold sidx=0, wv=+0.0, so padded
// groups gather row 0 with weight 0 (exact) and stay 8-deep to the end.
__device__ __forceinline__ void agg_node_pack(
    int node, int lane, const unsigned int* __restrict__ Tb,
    const unsigned short* __restrict__ ell, const int* __restrict__ deg,
    unsigned int* __restrict__ ellw,
    float bx, float by, float& ox, float& oy) {
  int dn = deg[node];
  float dd = rsqrtf((float)dn + 1.0f);
  unsigned sv = Tb[(size_t)node * 64 + lane];
  float wself = dd * dd;
  float ax = __int_as_float(sv << 16) * wself;
  float ay = __int_as_float(sv & 0xffff0000u) * wself;
  int m = min(dn, MAXDEG);
  int s0 = node << 6;
  int sidx = 0; float wv = 0.f;
  if (lane < m) {
    sidx = (int)ell[s0 + lane];       // coalesced (ELL row contiguous)
    wv = rsqrtf((float)deg[sidx] + 1.0f) * dd;   // scattered gather (only here)
    unsigned short hw = __builtin_bit_cast(unsigned short, (_Float16)wv);
    ellw[s0 + lane] = (unsigned)sidx | ((unsigned)hw << 16);
  }
  const int mt = (m + 7) & ~7;        // padded groups; j+q <= 63 always
  for (int j = 0; j < mt; j += 8) {
#pragma unroll
    for (int q = 0; q < 8; ++q) {     // 8 independent row gathers in flight
      int s = __builtin_amdgcn_readlane(sidx, j + q);
      float w = __int_as_float(__builtin_amdgcn_readlane(__float_as_int(wv), j + q));
      unsigned t = Tb[(size_t)s * 64 + lane];
      ax += w * __int_as_float(t << 16);
      ay += w * __int_as_float(t & 0xffff0000u);
    }
  }
  ox = fmaxf(ax + bx, 0.f);
  oy = fmaxf(ay + by, 0.f);
}

// ---------------- fused agg1 + gemm2, one node per wave ---------------------
// 3125 blocks x 16 waves = 50000 waves (full agg TLP), 16-row MFMA tile on
// W2 (8 active waves, 1 col-tile each, B direct from global fp32).
// r25: 2-node/wave variant was neutral — keep the simpler 1-node form.
__global__ __launch_bounds__(1024) void agg_gemm_kernel(
    const unsigned int* __restrict__ Tb, const unsigned short* __restrict__ ell,
    const int* __restrict__ deg, const float* __restrict__ bias,
    const float* __restrict__ W, unsigned int* __restrict__ ellw,
    unsigned short* __restrict__ T2) {
  __shared__ unsigned short sA[16 * PAD];   // 4.4 KB
  const int tid = threadIdx.x;
  const int lane = tid & 63;
  const int w = tid >> 6;            // 0..15 — one node per wave
  const int l15 = lane & 15;
  const int quad = lane >> 4;
  const int base = blockIdx.x * 16;  // 3125 * 16 = 50000 exactly

  {
    float2 b = ((const float2*)bias)[lane];
    float ox, oy;
    agg_node_pack(base + w, lane, Tb, ell, deg, ellw, b.x, b.y, ox, oy);
    *(unsigned*)(sA + w * PAD + lane * 2) =
        (unsigned)f2bf(ox) | ((unsigned)f2bf(oy) << 16);   // stride-1 uint: free
  }
  __syncthreads();

  f32x4 acc = (f32x4)(0.f);
  if (w < 8) {                       // wave w owns col-tile w (cols w*16..+16)
    const int ncol = w * 16 + l15;
#pragma unroll
    for (int ks = 0; ks < 4; ++ks) {
      const int koff = ks * 32 + quad * 8;
      bf16x8 a = *(const bf16x8*)(sA + l15 * PAD + koff);
      bf16x8 bfr;
      const float* wp = W + (size_t)koff * HID + ncol;
#pragma unroll
      for (int j = 0; j < 8; ++j) bfr[j] = (short)f2bf(wp[(size_t)j * HID]);
      acc = __builtin_amdgcn_mfma_f32_16x16x32_bf16(a, bfr, acc, 0, 0, 0);
    }
  }
  __syncthreads();                   // uniform barrier (no sync inside the if)
  if (w < 8) {
#pragma unroll
    for (int r = 0; r < 4; ++r)
      sA[(quad * 4 + r) * PAD + w * 16 + l15] = f2bf(acc[r]);
  }
  __syncthreads();
  if (tid < 256) {                   // 16 rows x 16 us8 chunks = 256
    int nrow = tid >> 4;
    int col = (tid & 15) * 8;
    *(us8*)(T2 + (size_t)(base + nrow) * HID + col) = *(const us8*)(sA + nrow * PAD + col);
  }
}

// ---------------- agg2: TWO nodes per wave, packed weights -> bf16 H --------
// r20/r22: 16 gathers in flight (2 nodes x 8) is the measured optimum.
// Tails via the pw=0 padding trick (row 0, weight +0.0 — exact).
__global__ __launch_bounds__(256) void aggregate_kernel(
    const unsigned int* __restrict__ Tb, const unsigned int* __restrict__ ellw,
    const int* __restrict__ deg, const float* __restrict__ bias,
    unsigned int* __restrict__ Hb) {
  int wid = (blockIdx.x * 256 + threadIdx.x) >> 6;
  int lane = threadIdx.x & 63;
  int n0 = wid * 2;
  if (n0 >= N_NODES) return;
  int n1 = n0 + 1;
  float2 b = ((const float2*)bias)[lane];
  int d0 = deg[n0], d1 = deg[n1];
  float r0 = rsqrtf((float)d0 + 1.f), r1 = rsqrtf((float)d1 + 1.f);
  unsigned sv0 = Tb[(size_t)n0 * 64 + lane];
  unsigned sv1 = Tb[(size_t)n1 * 64 + lane];
  float ax0 = __int_as_float(sv0 << 16) * (r0 * r0);
  float ay0 = __int_as_float(sv0 & 0xffff0000u) * (r0 * r0);
  float ax1 = __int_as_float(sv1 << 16) * (r1 * r1);
  float ay1 = __int_as_float(sv1 & 0xffff0000u) * (r1 * r1);
  int m0 = min(d0, MAXDEG), m1 = min(d1, MAXDEG);
  unsigned pw0 = 0, pw1 = 0;
  if (lane < m0) pw0 = ellw[(n0 << 6) + lane];   // coalesced
  if (lane < m1) pw1 = ellw[(n1 << 6) + lane];
  const int mt = (max(m0, m1) + 7) & ~7;
  for (int j = 0; j < mt; j += 8) {
#pragma unroll
    for (int q = 0; q < 8; ++q) {     // 16 independent row gathers in flight
      unsigned v0 = (unsigned)__builtin_amdgcn_readlane((int)pw0, j + q);
      unsigned v1 = (unsigned)__builtin_amdgcn_readlane((int)pw1, j + q);
      unsigned t0 = Tb[(size_t)(v0 & 0xffffu) * 64 + lane];
      unsigned t1 = Tb[(size_t)(v1 & 0xffffu) * 64 + lane];
      float w0 = (float)__builtin_bit_cast(_Float16, (unsigned short)(v0 >> 16));
      float w1 = (float)__builtin_bit_cast(_Float16, (unsigned short)(v1 >> 16));
      ax0 += w0 * __int_as_float(t0 << 16);
      ay0 += w0 * __int_as_float(t0 & 0xffff0000u);
      ax1 += w1 * __int_as_float(t1 << 16);
      ay1 += w1 * __int_as_float(t1 & 0xffff0000u);
    }
  }
  Hb[(size_t)n0 * 64 + lane] =
      (unsigned)f2bf(fmaxf(ax0 + b.x, 0.f)) |
      ((unsigned)f2bf(fmaxf(ay0 + b.y, 0.f)) << 16);
  Hb[(size_t)n1 * 64 + lane] =
      (unsigned)f2bf(fmaxf(ax1 + b.x, 0.f)) |
      ((unsigned)f2bf(fmaxf(ay1 + b.y, 0.f)) << 16);
}

// ---------------- pool partial sums: 4 blocks per graph -> fp32 atomics -----
__global__ __launch_bounds__(256) void pool_partial_kernel(
    const unsigned int* __restrict__ Hb, const int* __restrict__ start,
    float* __restrict__ pooled) {
  __shared__ float2 red[4][64];
  int g = blockIdx.x >> 2;
  int chunk = blockIdx.x & 3;
  int n0 = start[g], n1 = start[g + 1];
  int lane = threadIdx.x & 63, w = threadIdx.x >> 6;
  float ax = 0.f, ay = 0.f;
  for (int n = n0 + chunk * 4 + w; n < n1; n += 16) {
    unsigned h = Hb[(size_t)n * 64 + lane];
    ax += __int_as_float(h << 16);
    ay += __int_as_float(h & 0xffff0000u);
  }
  red[w][lane] = make_float2(ax, ay);
  __syncthreads();
  if (threadIdx.x < 64) {
    float2 a = red[0][lane], b = red[1][lane], c = red[2][lane], d = red[3][lane];
    atomicAdd(&pooled[g * HID + lane * 2],     a.x + b.x + c.x + d.x);
    atomicAdd(&pooled[g * HID + lane * 2 + 1], a.y + b.y + c.y + d.y);
  }
}

// ---------------- FC head + log_softmax on pooled sums (1 wave / graph) -----
__global__ __launch_bounds__(64) void head_kernel(
    const float* __restrict__ pooled, const int* __restrict__ start,
    const float* __restrict__ Wfc, const float* __restrict__ bfc,
    float* __restrict__ out) {
  int g = blockIdx.x;
  int lane = threadIdx.x;
  int o = lane & 15;
  float inv = 1.0f / fmaxf((float)(start[g + 1] - start[g]), 1.0f);
  float part = 0.f;
  for (int k = (lane >> 4); k < HID; k += 4)
    part += pooled[g * HID + k] * inv * Wfc[k * OUT_C + o];
  part += __shfl_xor(part, 16);
  part += __shfl_xor(part, 32);
  float logit = part + bfc[o];
  float m = logit;
#pragma unroll
  for (int d = 8; d >= 1; d >>= 1) m = fmaxf(m, __shfl_xor(m, d, 16));
  float e = __expf(logit - m);
  float s = e;
#pragma unroll
  for (int d = 8; d >= 1; d >>= 1) s += __shfl_xor(s, d, 16);
  float r = logit - m - __logf(s);
  if (lane < 16) out[g * OUT_C + o] = r;
}

extern "C" void kernel_launch(void* const* d_in, const int* in_sizes, int n_in,
                              void* d_out, int out_size, void* d_ws, size_t ws_size,
                              hipStream_t stream) {
  const float* x    = (const float*)d_in[0];
  const int*   ei   = (const int*)d_in[1];
  const int*   batch= (const int*)d_in[2];
  const float* W1   = (const float*)d_in[3];
  const float* b1   = (const float*)d_in[4];
  const float* W2   = (const float*)d_in[5];
  const float* b2   = (const float*)d_in[6];
  const float* Wfc  = (const float*)d_in[7];
  const float* bfc  = (const float*)d_in[8];
  float* out = (float*)d_out;
  const int* src = ei;              // edge_index[0]
  const int* dst = ei + N_EDGES;    // edge_index[1]

  char* p = (char*)d_ws;
  auto alloc = [&](size_t bytes) { char* r = p; p += (bytes + 255) & ~255ull; return r; };
  // degI and pooled adjacent -> a single memset covers both
  int*   degI   = (int*)alloc((size_t)N_NODES * 4);                           // 200192 B padded
  float* pooled = (float*)alloc((size_t)N_GRAPHS * HID * 4);                  // 65536 B
  int*   start  = (int*)alloc((N_GRAPHS + 1) * 4);
  unsigned short* ell = (unsigned short*)alloc((size_t)N_NODES * MAXDEG * 2); // 6.4 MB
  unsigned int*   ellw= (unsigned int*)alloc((size_t)N_NODES * MAXDEG * 4);   // 12.8 MB
  unsigned short* T   = (unsigned short*)alloc((size_t)N_NODES * HID * 2);    // 12.8 MB
  unsigned short* T2  = (unsigned short*)alloc((size_t)N_NODES * HID * 2);    // 12.8 MB
  unsigned short* Hb  = (unsigned short*)alloc((size_t)N_NODES * HID * 2);    // 12.8 MB

  hipMemsetAsync(degI, 0, ((size_t)N_NODES * 4 + 255 & ~255ull) +
                          (size_t)N_GRAPHS * HID * 4, stream);

  int agg_blocks = (N_NODES / 2 * 64 + 255) / 256;   // 2 nodes per wave

  mega_kernel<<<GB0 + 31, 256, 0, stream>>>(src, dst, degI, ell,
                                            batch, start, x, W1, T);
  agg_gemm_kernel<<<AGB, 1024, 0, stream>>>((const unsigned int*)T, ell, degI,
                                            b1, W2, ellw, T2);
  aggregate_kernel<<<agg_blocks, 256, 0, stream>>>((const unsigned int*)T2, ellw, degI, b2,
                                                   (unsigned int*)Hb);
  pool_partial_kernel<<<N_GRAPHS * 4, 256, 0, stream>>>((const unsigned int*)Hb, start,
                                                        pooled);
  head_kernel<<<N_GRAPHS, 64, 0, stream>>>(pooled, start, Wfc, bfc, out);
}

// Round 16
// 216.740 us; speedup vs baseline: 1.0134x; 1.0134x over previous
//
#include <hip/hip_runtime.h>

#define N_NODES  50000
#define N_EDGES  800000
#define HID      128
#define OUT_C    16
#define N_GRAPHS 128
#define MAXDEG   64     // r26: 32 didn't cut WRITE_SIZE; 64 is safe
#define NSLICE   6250   // N_NODES / 8; slice s owns [s*6250,(s+1)*6250)
#define EPB      1024   // = 4 edges/thread exactly (int4 fast path, r29)
#define AGB      3125   // agg_gemm blocks
#define PAD      136    // +8 bf16 pad -> frag reads 2-way (free) not 16-way

// r22 mega layout (kept): groups of 72 = 64 fill + 8 gemm; fi&7 == b&7
// preserves slice<->XCD alignment (r20: breaking it = +17.6MB writebacks).
// FLOOR EVIDENCE: r32 (8 chains/thread) regressed -> fill is L2-atomic-
// throughput-bound at ~49us. r23/r30/r31 pool-fusion all null-or-worse
// (CAS retry / per-op atomic traffic / LDS-reduction overhead). r27/r28:
// agg passes are gather-latency-bound (cross-XCD random 256B rows) — per-
// edge micro-op removal buys nothing. r26: mega's excess WRITE = scattered
// 2B-store sector granularity, intrinsic. r29: int4 single-wait fill loads
// 55.5->49.3us (the last real win).
#define GRP      72
#define NGRP     97     // full groups: 6208 fill + 776 gemm
#define GB0      6984   // NGRP*GRP; tail: 48 fill + 6 gemm + 1 bounds

typedef __attribute__((ext_vector_type(8))) short bf16x8;
typedef __attribute__((ext_vector_type(4))) float f32x4;
typedef __attribute__((ext_vector_type(4))) int i32x4;
typedef __attribute__((ext_vector_type(8))) unsigned short us8;
typedef __attribute__((ext_vector_type(4))) unsigned short us4;

__device__ __forceinline__ unsigned short f2bf(float f) {
  unsigned u = __float_as_uint(f);
  u += 0x7fffu + ((u >> 16) & 1u);   // RNE
  return (unsigned short)(u >> 16);
}

// ---------------- shared MFMA compute+store, 256-thread version -------------
// 16x16x32 MFMA; A: m=lane&15,k=quad*8+j (LDS); B: n=lane&15,k=quad*8+j
// loaded straight from global fp32 W[k][n] (L2-broadcast). C/D:
// col=lane&15,row=quad*4+reg.
// r18 lesson: NO nontemporal stores on T — gathered with ~16x reuse next.
__device__ __forceinline__ void gemm_compute_store(
    unsigned short* sA, const float* __restrict__ W,
    unsigned short* __restrict__ T, int base) {
  const int tid = threadIdx.x;
  const int lane = tid & 63;
  const int w = tid >> 6;
  const int l15 = lane & 15;
  const int quad = lane >> 4;
  __syncthreads();

  f32x4 acc[4][2];
#pragma unroll
  for (int nt = 0; nt < 4; ++nt)
#pragma unroll
    for (int c = 0; c < 2; ++c) acc[nt][c] = (f32x4)(0.f);

  const int ct0 = w * 2;
  const int ncol = ct0 * 16 + l15;
#pragma unroll
  for (int ks = 0; ks < 4; ++ks) {
    const int koff = ks * 32 + quad * 8;
    bf16x8 a[4], bfr[2];
#pragma unroll
    for (int c = 0; c < 2; ++c) {
      const float* wp = W + (size_t)koff * HID + ncol + c * 16;
#pragma unroll
      for (int j = 0; j < 8; ++j) bfr[c][j] = (short)f2bf(wp[(size_t)j * HID]);
    }
#pragma unroll
    for (int nt = 0; nt < 4; ++nt)
      a[nt] = *(const bf16x8*)(sA + (nt * 16 + l15) * PAD + koff);
#pragma unroll
    for (int nt = 0; nt < 4; ++nt)
#pragma unroll
      for (int c = 0; c < 2; ++c)
        acc[nt][c] = __builtin_amdgcn_mfma_f32_16x16x32_bf16(a[nt], bfr[c], acc[nt][c], 0, 0, 0);
  }
  __syncthreads();

#pragma unroll
  for (int nt = 0; nt < 4; ++nt)
#pragma unroll
    for (int c = 0; c < 2; ++c)
#pragma unroll
      for (int r = 0; r < 4; ++r)
        sA[(nt * 16 + quad * 4 + r) * PAD + (ct0 + c) * 16 + l15] = f2bf(acc[nt][c][r]);
  __syncthreads();
#pragma unroll
  for (int i = 0; i < 4; ++i) {
    int idx = tid + i * 256;
    int nrow = idx >> 4;
    int col = (idx & 15) * 8;
    int node = base + nrow;
    if (node < N_NODES)
      *(us8*)(T + (size_t)node * HID + col) = *(const us8*)(sA + nrow * PAD + col);
  }
}

// stage A from fp32 (convert to bf16): 64 rows x 32 float4 = 2048
// r22 (kept): NT loads — x is read-once streaming. ext-vector f32x4 required.
__device__ __forceinline__ void stage_a_f32(unsigned short* sA,
                                            const float* __restrict__ H, int base) {
#pragma unroll
  for (int i = 0; i < 8; ++i) {
    int idx = threadIdx.x + i * 256;
    int nrow = idx >> 5;
    int c4 = (idx & 31) * 4;
    f32x4 v = (f32x4)(0.f);
    int node = base + nrow;
    if (node < N_NODES)
      v = __builtin_nontemporal_load((const f32x4*)(H + (size_t)node * HID + c4));
    us4 b;
    b.x = f2bf(v.x); b.y = f2bf(v.y); b.z = f2bf(v.z); b.w = f2bf(v.w);
    *(us4*)(sA + nrow * PAD + c4) = b;
  }
}

// ---- mega: 97 groups of (64 fill + 8 gemm) + tail(48 fill + 6 gemm + bounds)
// r29 (kept): fill fast path — ONE i32x4 NT load each for 4 dst and 4 src
// (old loop had vmcnt(0) per iteration = 4 serialized HBM round-trips;
// 55.5->49.3us). 4 independent atomic->store chains follow.
__global__ __launch_bounds__(256) void mega_kernel(
    const int* __restrict__ src, const int* __restrict__ dst,
    int* __restrict__ deg, unsigned short* __restrict__ ell,
    const int* __restrict__ batch, int* __restrict__ start,
    const float* __restrict__ x, const float* __restrict__ W1,
    unsigned short* __restrict__ T) {
  __shared__ unsigned short sA[64 * PAD];   // 17.4 KB
  const int b = blockIdx.x;
  int fi = -1, gi = -1;
  if (b < GB0) {
    const int g = b / GRP, r = b % GRP;
    if (r < 64) fi = g * 64 + r;            // fi&7 == b&7 (64,72 both %8==0)
    else        gi = g * 8 + (r - 64);
  } else {
    const int r = b - GB0;                  // GB0%8==0 -> alignment kept
    if (r < 48)      fi = NGRP * 64 + r;
    else if (r < 54) gi = NGRP * 8 + (r - 48);
    // r==54 -> bounds
  }
  if (fi >= 0) {
    const int slice = fi & 7;
    const int e0 = (fi >> 3) * EPB;
    const unsigned lo = slice * NSLICE;
    if (e0 + EPB <= N_EDGES) {              // fast path: exactly 4 edges/thread
      const int eb = e0 + threadIdx.x * 4;
      i32x4 d4 = __builtin_nontemporal_load((const i32x4*)(dst + eb));
      i32x4 s4 = __builtin_nontemporal_load((const i32x4*)(src + eb));
#pragma unroll
      for (int i = 0; i < 4; ++i) {
        int d = d4[i];
        if ((unsigned)(d - lo) < (unsigned)NSLICE) {
          int p = atomicAdd(&deg[d], 1);
          if (p < MAXDEG) ell[(d << 6) + p] = (unsigned short)s4[i];
        }
      }
    } else {                                // tail chunk (256 edges)
      for (int e = e0 + threadIdx.x; e < N_EDGES; e += 256) {
        int d = dst[e];
        if ((unsigned)(d - lo) < (unsigned)NSLICE) {
          int p = atomicAdd(&deg[d], 1);
          if (p < MAXDEG) ell[(d << 6) + p] = (unsigned short)src[e];
        }
      }
    }
  } else if (gi >= 0) {
    const int base = gi * 64;
    stage_a_f32(sA, x, base);
    gemm_compute_store(sA, W1, T, base);
  } else {
    int t = threadIdx.x;                       // graph bounds (batch sorted)
    if (t <= N_GRAPHS) {
      int lo = 0, hi = N_NODES;
      while (lo < hi) {
        int mid = (lo + hi) >> 1;
        if (batch[mid] < t) lo = mid + 1; else hi = mid;
      }
      start[t] = lo;
    }
  }
}

// ------- agg core, pass 1: gathers deg[src] (scattered, once) + PACKS -------
// lane owns 2 bf16 channels; coalesced ell load + scattered deg gather, then
// readlane-broadcast with 8 independent row gathers in flight. Packs
// (src | fp16(weight)<<16) into ellw so pass 2 never touches deg[].
// r20 (kept): padded-tail — lanes >= m hold sidx=0, wv=+0.0, so padded
// groups gather row 0 with weight 0 (exact) and stay 8-deep to the end.
__device__ __forceinline__ void agg_node_pack(
    int node, int lane, const unsigned int* __restrict__ Tb,
    const unsigned short* __restrict__ ell, const int* __restrict__ deg,
    unsigned int* __restrict__ ellw,
    float bx, float by, float& ox, float& oy) {
  int dn = deg[node];
  float dd = rsqrtf((float)dn + 1.0f);
  unsigned sv = Tb[(size_t)node * 64 + lane];
  float wself = dd * dd;
  float ax = __int_as_float(sv << 16) * wself;
  float ay = __int_as_float(sv & 0xffff0000u) * wself;
  int m = min(dn, MAXDEG);
  int s0 = node << 6;
  int sidx = 0; float wv = 0.f;
  if (lane < m) {
    sidx = (int)ell[s0 + lane];       // coalesced (ELL row contiguous)
    wv = rsqrtf((float)deg[sidx] + 1.0f) * dd;   // scattered gather (only here)
    unsigned short hw = __builtin_bit_cast(unsigned short, (_Float16)wv);
    ellw[s0 + lane] = (unsigned)sidx | ((unsigned)hw << 16);
  }
  const int mt = (m + 7) & ~7;        // padded groups; j+q <= 63 always
  for (int j = 0; j < mt; j += 8) {
#pragma unroll
    for (int q = 0; q < 8; ++q) {     // 8 independent row gathers in flight
      int s = __builtin_amdgcn_readlane(sidx, j + q);
      float w = __int_as_float(__builtin_amdgcn_readlane(__float_as_int(wv), j + q));
      unsigned t = Tb[(size_t)s * 64 + lane];
      ax += w * __int_as_float(t << 16);
      ay += w * __int_as_float(t & 0xffff0000u);
    }
  }
  ox = fmaxf(ax + bx, 0.f);
  oy = fmaxf(ay + by, 0.f);
}

// ---------------- fused agg1 + gemm2, one node per wave ---------------------
// 3125 blocks x 16 waves = 50000 waves (full agg TLP), 16-row MFMA tile on
// W2 (8 active waves, 1 col-tile each, B direct from global fp32).
// r25: 2-node/wave variant was neutral — keep the simpler 1-node form.
__global__ __launch_bounds__(1024) void agg_gemm_kernel(
    const unsigned int* __restrict__ Tb, const unsigned short* __restrict__ ell,
    const int* __restrict__ deg, const float* __restrict__ bias,
    const float* __restrict__ W, unsigned int* __restrict__ ellw,
    unsigned short* __restrict__ T2) {
  __shared__ unsigned short sA[16 * PAD];   // 4.4 KB
  const int tid = threadIdx.x;
  const int lane = tid & 63;
  const int w = tid >> 6;            // 0..15 — one node per wave
  const int l15 = lane & 15;
  const int quad = lane >> 4;
  const int base = blockIdx.x * 16;  // 3125 * 16 = 50000 exactly

  {
    float2 b = ((const float2*)bias)[lane];
    float ox, oy;
    agg_node_pack(base + w, lane, Tb, ell, deg, ellw, b.x, b.y, ox, oy);
    *(unsigned*)(sA + w * PAD + lane * 2) =
        (unsigned)f2bf(ox) | ((unsigned)f2bf(oy) << 16);   // stride-1 uint: free
  }
  __syncthreads();

  f32x4 acc = (f32x4)(0.f);
  if (w < 8) {                       // wave w owns col-tile w (cols w*16..+16)
    const int ncol = w * 16 + l15;
#pragma unroll
    for (int ks = 0; ks < 4; ++ks) {
      const int koff = ks * 32 + quad * 8;
      bf16x8 a = *(const bf16x8*)(sA + l15 * PAD + koff);
      bf16x8 bfr;
      const float* wp = W + (size_t)koff * HID + ncol;
#pragma unroll
      for (int j = 0; j < 8; ++j) bfr[j] = (short)f2bf(wp[(size_t)j * HID]);
      acc = __builtin_amdgcn_mfma_f32_16x16x32_bf16(a, bfr, acc, 0, 0, 0);
    }
  }
  __syncthreads();                   // uniform barrier (no sync inside the if)
  if (w < 8) {
#pragma unroll
    for (int r = 0; r < 4; ++r)
      sA[(quad * 4 + r) * PAD + w * 16 + l15] = f2bf(acc[r]);
  }
  __syncthreads();
  if (tid < 256) {                   // 16 rows x 16 us8 chunks = 256
    int nrow = tid >> 4;
    int col = (tid & 15) * 8;
    *(us8*)(T2 + (size_t)(base + nrow) * HID + col) = *(const us8*)(sA + nrow * PAD + col);
  }
}

// ---------------- agg2: TWO nodes per wave, packed weights -> bf16 H --------
// r20/r22: 16 gathers in flight (2 nodes x 8) is the measured optimum.
// Tails via the pw=0 padding trick (row 0, weight +0.0 — exact).
__global__ __launch_bounds__(256) void aggregate_kernel(
    const unsigned int* __restrict__ Tb, const unsigned int* __restrict__ ellw,
    const int* __restrict__ deg, const float* __restrict__ bias,
    unsigned int* __restrict__ Hb) {
  int wid = (blockIdx.x * 256 + threadIdx.x) >> 6;
  int lane = threadIdx.x & 63;
  int n0 = wid * 2;
  if (n0 >= N_NODES) return;
  int n1 = n0 + 1;
  float2 b = ((const float2*)bias)[lane];
  int d0 = deg[n0], d1 = deg[n1];
  float r0 = rsqrtf((float)d0 + 1.f), r1 = rsqrtf((float)d1 + 1.f);
  unsigned sv0 = Tb[(size_t)n0 * 64 + lane];
  unsigned sv1 = Tb[(size_t)n1 * 64 + lane];
  float ax0 = __int_as_float(sv0 << 16) * (r0 * r0);
  float ay0 = __int_as_float(sv0 & 0xffff0000u) * (r0 * r0);
  float ax1 = __int_as_float(sv1 << 16) * (r1 * r1);
  float ay1 = __int_as_float(sv1 & 0xffff0000u) * (r1 * r1);
  int m0 = min(d0, MAXDEG), m1 = min(d1, MAXDEG);
  unsigned pw0 = 0, pw1 = 0;
  if (lane < m0) pw0 = ellw[(n0 << 6) + lane];   // coalesced
  if (lane < m1) pw1 = ellw[(n1 << 6) + lane];
  const int mt = (max(m0, m1) + 7) & ~7;
  for (int j = 0; j < mt; j += 8) {
#pragma unroll
    for (int q = 0; q < 8; ++q) {     // 16 independent row gathers in flight
      unsigned v0 = (unsigned)__builtin_amdgcn_readlane((int)pw0, j + q);
      unsigned v1 = (unsigned)__builtin_amdgcn_readlane((int)pw1, j + q);
      unsigned t0 = Tb[(size_t)(v0 & 0xffffu) * 64 + lane];
      unsigned t1 = Tb[(size_t)(v1 & 0xffffu) * 64 + lane];
      float w0 = (float)__builtin_bit_cast(_Float16, (unsigned short)(v0 >> 16));
      float w1 = (float)__builtin_bit_cast(_Float16, (unsigned short)(v1 >> 16));
      ax0 += w0 * __int_as_float(t0 << 16);
      ay0 += w0 * __int_as_float(t0 & 0xffff0000u);
      ax1 += w1 * __int_as_float(t1 << 16);
      ay1 += w1 * __int_as_float(t1 & 0xffff0000u);
    }
  }
  Hb[(size_t)n0 * 64 + lane] =
      (unsigned)f2bf(fmaxf(ax0 + b.x, 0.f)) |
      ((unsigned)f2bf(fmaxf(ay0 + b.y, 0.f)) << 16);
  Hb[(size_t)n1 * 64 + lane] =
      (unsigned)f2bf(fmaxf(ax1 + b.x, 0.f)) |
      ((unsigned)f2bf(fmaxf(ay1 + b.y, 0.f)) << 16);
}

// ---------------- pool partial sums: 4 blocks per graph -> fp32 atomics -----
__global__ __launch_bounds__(256) void pool_partial_kernel(
    const unsigned int* __restrict__ Hb, const int* __restrict__ start,
    float* __restrict__ pooled) {
  __shared__ float2 red[4][64];
  int g = blockIdx.x >> 2;
  int chunk = blockIdx.x & 3;
  int n0 = start[g], n1 = start[g + 1];
  int lane = threadIdx.x & 63, w = threadIdx.x >> 6;
  float ax = 0.f, ay = 0.f;
  for (int n = n0 + chunk * 4 + w; n < n1; n += 16) {
    unsigned h = Hb[(size_t)n * 64 + lane];
    ax += __int_as_float(h << 16);
    ay += __int_as_float(h & 0xffff0000u);
  }
  red[w][lane] = make_float2(ax, ay);
  __syncthreads();
  if (threadIdx.x < 64) {
    float2 a = red[0][lane], b = red[1][lane], c = red[2][lane], d = red[3][lane];
    atomicAdd(&pooled[g * HID + lane * 2],     a.x + b.x + c.x + d.x);
    atomicAdd(&pooled[g * HID + lane * 2 + 1], a.y + b.y + c.y + d.y);
  }
}

// ---------------- FC head + log_softmax on pooled sums (1 wave / graph) -----
__global__ __launch_bounds__(64) void head_kernel(
    const float* __restrict__ pooled, const int* __restrict__ start,
    const float* __restrict__ Wfc, const float* __restrict__ bfc,
    float* __restrict__ out) {
  int g = blockIdx.x;
  int lane = threadIdx.x;
  int o = lane & 15;
  float inv = 1.0f / fmaxf((float)(start[g + 1] - start[g]), 1.0f);
  float part = 0.f;
  for (int k = (lane >> 4); k < HID; k += 4)
    part += pooled[g * HID + k] * inv * Wfc[k * OUT_C + o];
  part += __shfl_xor(part, 16);
  part += __shfl_xor(part, 32);
  float logit = part + bfc[o];
  float m = logit;
#pragma unroll
  for (int d = 8; d >= 1; d >>= 1) m = fmaxf(m, __shfl_xor(m, d, 16));
  float e = __expf(logit - m);
  float s = e;
#pragma unroll
  for (int d = 8; d >= 1; d >>= 1) s += __shfl_xor(s, d, 16);
  float r = logit - m - __logf(s);
  if (lane < 16) out[g * OUT_C + o] = r;
}

extern "C" void kernel_launch(void* const* d_in, const int* in_sizes, int n_in,
                              void* d_out, int out_size, void* d_ws, size_t ws_size,
                              hipStream_t stream) {
  const float* x    = (const float*)d_in[0];
  const int*   ei   = (const int*)d_in[1];
  const int*   batch= (const int*)d_in[2];
  const float* W1   = (const float*)d_in[3];
  const float* b1   = (const float*)d_in[4];
  const float* W2   = (const float*)d_in[5];
  const float* b2   = (const float*)d_in[6];
  const float* Wfc  = (const float*)d_in[7];
  const float* bfc  = (const float*)d_in[8];
  float* out = (float*)d_out;
  const int* src = ei;              // edge_index[0]
  const int* dst = ei + N_EDGES;    // edge_index[1]

  char* p = (char*)d_ws;
  auto alloc = [&](size_t bytes) { char* r = p; p += (bytes + 255) & ~255ull; return r; };
  // degI and pooled adjacent -> a single memset covers both
  int*   degI   = (int*)alloc((size_t)N_NODES * 4);                           // 200192 B padded
  float* pooled = (float*)alloc((size_t)N_GRAPHS * HID * 4);                  // 65536 B
  int*   start  = (int*)alloc((N_GRAPHS + 1) * 4);
  unsigned short* ell = (unsigned short*)alloc((size_t)N_NODES * MAXDEG * 2); // 6.4 MB
  unsigned int*   ellw= (unsigned int*)alloc((size_t)N_NODES * MAXDEG * 4);   // 12.8 MB
  unsigned short* T   = (unsigned short*)alloc((size_t)N_NODES * HID * 2);    // 12.8 MB
  unsigned short* T2  = (unsigned short*)alloc((size_t)N_NODES * HID * 2);    // 12.8 MB
  unsigned short* Hb  = (unsigned short*)alloc((size_t)N_NODES * HID * 2);    // 12.8 MB

  hipMemsetAsync(degI, 0, ((size_t)N_NODES * 4 + 255 & ~255ull) +
                          (size_t)N_GRAPHS * HID * 4, stream);

  int agg_blocks = (N_NODES / 2 * 64 + 255) / 256;   // 2 nodes per wave

  mega_kernel<<<GB0 + 55, 256, 0, stream>>>(src, dst, degI, ell,
                                            batch, start, x, W1, T);
  agg_gemm_kernel<<<AGB, 1024, 0, stream>>>((const unsigned int*)T, ell, degI,
                                            b1, W2, ellw, T2);
  aggregate_kernel<<<agg_blocks, 256, 0, stream>>>((const unsigned int*)T2, ellw, degI, b2,
                                                   (unsigned int*)Hb);
  pool_partial_kernel<<<N_GRAPHS * 4, 256, 0, stream>>>((const unsigned int*)Hb, start,
                                                        pooled);
  head_kernel<<<N_GRAPHS, 64, 0, stream>>>(pooled, start, Wfc, bfc, out);
}

// Round 17
// 215.880 us; speedup vs baseline: 1.0174x; 1.0040x over previous
//
#include <hip/hip_runtime.h>

#define N_NODES  50000
#define N_EDGES  800000
#define HID      128
#define OUT_C    16
#define N_GRAPHS 128
#define MAXDEG   64     // r26: 32 didn't cut WRITE_SIZE; 64 is safe
#define NSLICE   6250   // N_NODES / 8; slice s owns [s*6250,(s+1)*6250)
#define EPB      1024   // = 4 edges/thread exactly (int4 fast path, r29)
#define AGB      3125   // agg_gemm blocks
#define PAD      136    // +8 bf16 pad -> frag reads 2-way (free) not 16-way

// r22 mega layout (kept): groups of 72 = 64 fill + 8 gemm; fi&7 == b&7
// preserves slice<->XCD alignment (r20: breaking it = +17.6MB writebacks).
// FLOOR EVIDENCE: r32 (8 chains/thread) regressed -> fill is L2-atomic-
// throughput-bound at ~49us. r23/r30/r31 aggregate->pool fusion all null-
// or-worse (CAS retry / per-op atomic traffic / LDS-reduction overhead).
// r27/r28: agg passes are gather-latency-bound — micro-op removal buys 0.
// r26: mega's excess WRITE = scattered-2B sector granularity, intrinsic.
// r29: int4 single-wait fill loads 55.5->49.3us. r34: pool+head fused into
// one 128-block kernel (different from aggregate->pool fusion: no atomics).
#define GRP      72
#define NGRP     97     // full groups: 6208 fill + 776 gemm
#define GB0      6984   // NGRP*GRP; tail: 48 fill + 6 gemm + 1 bounds

typedef __attribute__((ext_vector_type(8))) short bf16x8;
typedef __attribute__((ext_vector_type(4))) float f32x4;
typedef __attribute__((ext_vector_type(4))) int i32x4;
typedef __attribute__((ext_vector_type(8))) unsigned short us8;
typedef __attribute__((ext_vector_type(4))) unsigned short us4;

__device__ __forceinline__ unsigned short f2bf(float f) {
  unsigned u = __float_as_uint(f);
  u += 0x7fffu + ((u >> 16) & 1u);   // RNE
  return (unsigned short)(u >> 16);
}

// ---------------- shared MFMA compute+store, 256-thread version -------------
// 16x16x32 MFMA; A: m=lane&15,k=quad*8+j (LDS); B: n=lane&15,k=quad*8+j
// loaded straight from global fp32 W[k][n] (L2-broadcast). C/D:
// col=lane&15,row=quad*4+reg.
// r18 lesson: NO nontemporal stores on T — gathered with ~16x reuse next.
__device__ __forceinline__ void gemm_compute_store(
    unsigned short* sA, const float* __restrict__ W,
    unsigned short* __restrict__ T, int base) {
  const int tid = threadIdx.x;
  const int lane = tid & 63;
  const int w = tid >> 6;
  const int l15 = lane & 15;
  const int quad = lane >> 4;
  __syncthreads();

  f32x4 acc[4][2];
#pragma unroll
  for (int nt = 0; nt < 4; ++nt)
#pragma unroll
    for (int c = 0; c < 2; ++c) acc[nt][c] = (f32x4)(0.f);

  const int ct0 = w * 2;
  const int ncol = ct0 * 16 + l15;
#pragma unroll
  for (int ks = 0; ks < 4; ++ks) {
    const int koff = ks * 32 + quad * 8;
    bf16x8 a[4], bfr[2];
#pragma unroll
    for (int c = 0; c < 2; ++c) {
      const float* wp = W + (size_t)koff * HID + ncol + c * 16;
#pragma unroll
      for (int j = 0; j < 8; ++j) bfr[c][j] = (short)f2bf(wp[(size_t)j * HID]);
    }
#pragma unroll
    for (int nt = 0; nt < 4; ++nt)
      a[nt] = *(const bf16x8*)(sA + (nt * 16 + l15) * PAD + koff);
#pragma unroll
    for (int nt = 0; nt < 4; ++nt)
#pragma unroll
      for (int c = 0; c < 2; ++c)
        acc[nt][c] = __builtin_amdgcn_mfma_f32_16x16x32_bf16(a[nt], bfr[c], acc[nt][c], 0, 0, 0);
  }
  __syncthreads();

#pragma unroll
  for (int nt = 0; nt < 4; ++nt)
#pragma unroll
    for (int c = 0; c < 2; ++c)
#pragma unroll
      for (int r = 0; r < 4; ++r)
        sA[(nt * 16 + quad * 4 + r) * PAD + (ct0 + c) * 16 + l15] = f2bf(acc[nt][c][r]);
  __syncthreads();
#pragma unroll
  for (int i = 0; i < 4; ++i) {
    int idx = tid + i * 256;
    int nrow = idx >> 4;
    int col = (idx & 15) * 8;
    int node = base + nrow;
    if (node < N_NODES)
      *(us8*)(T + (size_t)node * HID + col) = *(const us8*)(sA + nrow * PAD + col);
  }
}

// stage A from fp32 (convert to bf16): 64 rows x 32 float4 = 2048
// r22 (kept): NT loads — x is read-once streaming. ext-vector f32x4 required.
__device__ __forceinline__ void stage_a_f32(unsigned short* sA,
                                            const float* __restrict__ H, int base) {
#pragma unroll
  for (int i = 0; i < 8; ++i) {
    int idx = threadIdx.x + i * 256;
    int nrow = idx >> 5;
    int c4 = (idx & 31) * 4;
    f32x4 v = (f32x4)(0.f);
    int node = base + nrow;
    if (node < N_NODES)
      v = __builtin_nontemporal_load((const f32x4*)(H + (size_t)node * HID + c4));
    us4 b;
    b.x = f2bf(v.x); b.y = f2bf(v.y); b.z = f2bf(v.z); b.w = f2bf(v.w);
    *(us4*)(sA + nrow * PAD + c4) = b;
  }
}

// ---- mega: 97 groups of (64 fill + 8 gemm) + tail(48 fill + 6 gemm + bounds)
// r29 (kept): fill fast path — ONE i32x4 NT load each for 4 dst and 4 src
// (old loop had vmcnt(0) per iteration = 4 serialized HBM round-trips;
// 55.5->49.3us). 4 independent atomic->store chains follow.
__global__ __launch_bounds__(256) void mega_kernel(
    const int* __restrict__ src, const int* __restrict__ dst,
    int* __restrict__ deg, unsigned short* __restrict__ ell,
    const int* __restrict__ batch, int* __restrict__ start,
    const float* __restrict__ x, const float* __restrict__ W1,
    unsigned short* __restrict__ T) {
  __shared__ unsigned short sA[64 * PAD];   // 17.4 KB
  const int b = blockIdx.x;
  int fi = -1, gi = -1;
  if (b < GB0) {
    const int g = b / GRP, r = b % GRP;
    if (r < 64) fi = g * 64 + r;            // fi&7 == b&7 (64,72 both %8==0)
    else        gi = g * 8 + (r - 64);
  } else {
    const int r = b - GB0;                  // GB0%8==0 -> alignment kept
    if (r < 48)      fi = NGRP * 64 + r;
    else if (r < 54) gi = NGRP * 8 + (r - 48);
    // r==54 -> bounds
  }
  if (fi >= 0) {
    const int slice = fi & 7;
    const int e0 = (fi >> 3) * EPB;
    const unsigned lo = slice * NSLICE;
    if (e0 + EPB <= N_EDGES) {              // fast path: exactly 4 edges/thread
      const int eb = e0 + threadIdx.x * 4;
      i32x4 d4 = __builtin_nontemporal_load((const i32x4*)(dst + eb));
      i32x4 s4 = __builtin_nontemporal_load((const i32x4*)(src + eb));
#pragma unroll
      for (int i = 0; i < 4; ++i) {
        int d = d4[i];
        if ((unsigned)(d - lo) < (unsigned)NSLICE) {
          int p = atomicAdd(&deg[d], 1);
          if (p < MAXDEG) ell[(d << 6) + p] = (unsigned short)s4[i];
        }
      }
    } else {                                // tail chunk (256 edges)
      for (int e = e0 + threadIdx.x; e < N_EDGES; e += 256) {
        int d = dst[e];
        if ((unsigned)(d - lo) < (unsigned)NSLICE) {
          int p = atomicAdd(&deg[d], 1);
          if (p < MAXDEG) ell[(d << 6) + p] = (unsigned short)src[e];
        }
      }
    }
  } else if (gi >= 0) {
    const int base = gi * 64;
    stage_a_f32(sA, x, base);
    gemm_compute_store(sA, W1, T, base);
  } else {
    int t = threadIdx.x;                       // graph bounds (batch sorted)
    if (t <= N_GRAPHS) {
      int lo = 0, hi = N_NODES;
      while (lo < hi) {
        int mid = (lo + hi) >> 1;
        if (batch[mid] < t) lo = mid + 1; else hi = mid;
      }
      start[t] = lo;
    }
  }
}

// ------- agg core, pass 1: gathers deg[src] (scattered, once) + PACKS -------
// lane owns 2 bf16 channels; coalesced ell load + scattered deg gather, then
// readlane-broadcast with 8 independent row gathers in flight. Packs
// (src | fp16(weight)<<16) into ellw so pass 2 never touches deg[].
// r20 (kept): padded-tail — lanes >= m hold sidx=0, wv=+0.0, so padded
// groups gather row 0 with weight 0 (exact) and stay 8-deep to the end.
__device__ __forceinline__ void agg_node_pack(
    int node, int lane, const unsigned int* __restrict__ Tb,
    const unsigned short* __restrict__ ell, const int* __restrict__ deg,
    unsigned int* __restrict__ ellw,
    float bx, float by, float& ox, float& oy) {
  int dn = deg[node];
  float dd = rsqrtf((float)dn + 1.0f);
  unsigned sv = Tb[(size_t)node * 64 + lane];
  float wself = dd * dd;
  float ax = __int_as_float(sv << 16) * wself;
  float ay = __int_as_float(sv & 0xffff0000u) * wself;
  int m = min(dn, MAXDEG);
  int s0 = node << 6;
  int sidx = 0; float wv = 0.f;
  if (lane < m) {
    sidx = (int)ell[s0 + lane];       // coalesced (ELL row contiguous)
    wv = rsqrtf((float)deg[sidx] + 1.0f) * dd;   // scattered gather (only here)
    unsigned short hw = __builtin_bit_cast(unsigned short, (_Float16)wv);
    ellw[s0 + lane] = (unsigned)sidx | ((unsigned)hw << 16);
  }
  const int mt = (m + 7) & ~7;        // padded groups; j+q <= 63 always
  for (int j = 0; j < mt; j += 8) {
#pragma unroll
    for (int q = 0; q < 8; ++q) {     // 8 independent row gathers in flight
      int s = __builtin_amdgcn_readlane(sidx, j + q);
      float w = __int_as_float(__builtin_amdgcn_readlane(__float_as_int(wv), j + q));
      unsigned t = Tb[(size_t)s * 64 + lane];
      ax += w * __int_as_float(t << 16);
      ay += w * __int_as_float(t & 0xffff0000u);
    }
  }
  ox = fmaxf(ax + bx, 0.f);
  oy = fmaxf(ay + by, 0.f);
}

// ---------------- fused agg1 + gemm2, one node per wave ---------------------
// 3125 blocks x 16 waves = 50000 waves (full agg TLP), 16-row MFMA tile on
// W2 (8 active waves, 1 col-tile each, B direct from global fp32).
// r25: 2-node/wave variant was neutral — keep the simpler 1-node form.
__global__ __launch_bounds__(1024) void agg_gemm_kernel(
    const unsigned int* __restrict__ Tb, const unsigned short* __restrict__ ell,
    const int* __restrict__ deg, const float* __restrict__ bias,
    const float* __restrict__ W, unsigned int* __restrict__ ellw,
    unsigned short* __restrict__ T2) {
  __shared__ unsigned short sA[16 * PAD];   // 4.4 KB
  const int tid = threadIdx.x;
  const int lane = tid & 63;
  const int w = tid >> 6;            // 0..15 — one node per wave
  const int l15 = lane & 15;
  const int quad = lane >> 4;
  const int base = blockIdx.x * 16;  // 3125 * 16 = 50000 exactly

  {
    float2 b = ((const float2*)bias)[lane];
    float ox, oy;
    agg_node_pack(base + w, lane, Tb, ell, deg, ellw, b.x, b.y, ox, oy);
    *(unsigned*)(sA + w * PAD + lane * 2) =
        (unsigned)f2bf(ox) | ((unsigned)f2bf(oy) << 16);   // stride-1 uint: free
  }
  __syncthreads();

  f32x4 acc = (f32x4)(0.f);
  if (w < 8) {                       // wave w owns col-tile w (cols w*16..+16)
    const int ncol = w * 16 + l15;
#pragma unroll
    for (int ks = 0; ks < 4; ++ks) {
      const int koff = ks * 32 + quad * 8;
      bf16x8 a = *(const bf16x8*)(sA + l15 * PAD + koff);
      bf16x8 bfr;
      const float* wp = W + (size_t)koff * HID + ncol;
#pragma unroll
      for (int j = 0; j < 8; ++j) bfr[j] = (short)f2bf(wp[(size_t)j * HID]);
      acc = __builtin_amdgcn_mfma_f32_16x16x32_bf16(a, bfr, acc, 0, 0, 0);
    }
  }
  __syncthreads();                   // uniform barrier (no sync inside the if)
  if (w < 8) {
#pragma unroll
    for (int r = 0; r < 4; ++r)
      sA[(quad * 4 + r) * PAD + w * 16 + l15] = f2bf(acc[r]);
  }
  __syncthreads();
  if (tid < 256) {                   // 16 rows x 16 us8 chunks = 256
    int nrow = tid >> 4;
    int col = (tid & 15) * 8;
    *(us8*)(T2 + (size_t)(base + nrow) * HID + col) = *(const us8*)(sA + nrow * PAD + col);
  }
}

// ---------------- agg2: TWO nodes per wave, packed weights -> bf16 H --------
// r20/r22: 16 gathers in flight (2 nodes x 8) is the measured optimum.
// Tails via the pw=0 padding trick (row 0, weight +0.0 — exact).
__global__ __launch_bounds__(256) void aggregate_kernel(
    const unsigned int* __restrict__ Tb, const unsigned int* __restrict__ ellw,
    const int* __restrict__ deg, const float* __restrict__ bias,
    unsigned int* __restrict__ Hb) {
  int wid = (blockIdx.x * 256 + threadIdx.x) >> 6;
  int lane = threadIdx.x & 63;
  int n0 = wid * 2;
  if (n0 >= N_NODES) return;
  int n1 = n0 + 1;
  float2 b = ((const float2*)bias)[lane];
  int d0 = deg[n0], d1 = deg[n1];
  float r0 = rsqrtf((float)d0 + 1.f), r1 = rsqrtf((float)d1 + 1.f);
  unsigned sv0 = Tb[(size_t)n0 * 64 + lane];
  unsigned sv1 = Tb[(size_t)n1 * 64 + lane];
  float ax0 = __int_as_float(sv0 << 16) * (r0 * r0);
  float ay0 = __int_as_float(sv0 & 0xffff0000u) * (r0 * r0);
  float ax1 = __int_as_float(sv1 << 16) * (r1 * r1);
  float ay1 = __int_as_float(sv1 & 0xffff0000u) * (r1 * r1);
  int m0 = min(d0, MAXDEG), m1 = min(d1, MAXDEG);
  unsigned pw0 = 0, pw1 = 0;
  if (lane < m0) pw0 = ellw[(n0 << 6) + lane];   // coalesced
  if (lane < m1) pw1 = ellw[(n1 << 6) + lane];
  const int mt = (max(m0, m1) + 7) & ~7;
  for (int j = 0; j < mt; j += 8) {
#pragma unroll
    for (int q = 0; q < 8; ++q) {     // 16 independent row gathers in flight
      unsigned v0 = (unsigned)__builtin_amdgcn_readlane((int)pw0, j + q);
      unsigned v1 = (unsigned)__builtin_amdgcn_readlane((int)pw1, j + q);
      unsigned t0 = Tb[(size_t)(v0 & 0xffffu) * 64 + lane];
      unsigned t1 = Tb[(size_t)(v1 & 0xffffu) * 64 + lane];
      float w0 = (float)__builtin_bit_cast(_Float16, (unsigned short)(v0 >> 16));
      float w1 = (float)__builtin_bit_cast(_Float16, (unsigned short)(v1 >> 16));
      ax0 += w0 * __int_as_float(t0 << 16);
      ay0 += w0 * __int_as_float(t0 & 0xffff0000u);
      ax1 += w1 * __int_as_float(t1 << 16);
      ay1 += w1 * __int_as_float(t1 & 0xffff0000u);
    }
  }
  Hb[(size_t)n0 * 64 + lane] =
      (unsigned)f2bf(fmaxf(ax0 + b.x, 0.f)) |
      ((unsigned)f2bf(fmaxf(ay0 + b.y, 0.f)) << 16);
  Hb[(size_t)n1 * 64 + lane] =
      (unsigned)f2bf(fmaxf(ax1 + b.x, 0.f)) |
      ((unsigned)f2bf(fmaxf(ay1 + b.y, 0.f)) << 16);
}

// ------- FUSED pool + FC head + log_softmax: 1 block per graph (r34) --------
// 16 waves stride the graph's Hb rows (coalesced 256B/row), LDS tree-reduce
// 16 partials -> 128 channels, wave 0 computes the head from LDS. Replaces
// pool_partial (512 blocks + fp32 atomics + pooled buffer) + head dispatch.
__global__ __launch_bounds__(1024) void pool_head_kernel(
    const unsigned int* __restrict__ Hb, const int* __restrict__ start,
    const float* __restrict__ Wfc, const float* __restrict__ bfc,
    float* __restrict__ out) {
  __shared__ float2 red[16][64];     // 8 KB
  __shared__ float pooled_l[HID];
  const int g = blockIdx.x;
  const int tid = threadIdx.x;
  const int lane = tid & 63;
  const int wid = tid >> 6;          // 0..15
  const int n0 = start[g], n1 = start[g + 1];
  float ax = 0.f, ay = 0.f;
  for (int n = n0 + wid; n < n1; n += 16) {
    unsigned h = Hb[(size_t)n * 64 + lane];
    ax += __int_as_float(h << 16);
    ay += __int_as_float(h & 0xffff0000u);
  }
  red[wid][lane] = make_float2(ax, ay);
  __syncthreads();
  if (tid < 64) {
    float sx = 0.f, sy = 0.f;
#pragma unroll
    for (int i = 0; i < 16; ++i) {
      float2 v = red[i][tid];
      sx += v.x; sy += v.y;
    }
    float inv = 1.0f / fmaxf((float)(n1 - n0), 1.0f);
    pooled_l[tid * 2]     = sx * inv;
    pooled_l[tid * 2 + 1] = sy * inv;
    // head on wave 0 (wave-synchronous; LDS read-after-write within wave ok)
    int o = tid & 15;
    float part = 0.f;
    for (int k = (tid >> 4); k < HID; k += 4)
      part += pooled_l[k] * Wfc[k * OUT_C + o];
    part += __shfl_xor(part, 16);
    part += __shfl_xor(part, 32);
    float logit = part + bfc[o];
    float m = logit;
#pragma unroll
    for (int d = 8; d >= 1; d >>= 1) m = fmaxf(m, __shfl_xor(m, d, 16));
    float e = __expf(logit - m);
    float s = e;
#pragma unroll
    for (int d = 8; d >= 1; d >>= 1) s += __shfl_xor(s, d, 16);
    float r = logit - m - __logf(s);
    if (tid < 16) out[g * OUT_C + o] = r;
  }
}

extern "C" void kernel_launch(void* const* d_in, const int* in_sizes, int n_in,
                              void* d_out, int out_size, void* d_ws, size_t ws_size,
                              hipStream_t stream) {
  const float* x    = (const float*)d_in[0];
  const int*   ei   = (const int*)d_in[1];
  const int*   batch= (const int*)d_in[2];
  const float* W1   = (const float*)d_in[3];
  const float* b1   = (const float*)d_in[4];
  const float* W2   = (const float*)d_in[5];
  const float* b2   = (const float*)d_in[6];
  const float* Wfc  = (const float*)d_in[7];
  const float* bfc  = (const float*)d_in[8];
  float* out = (float*)d_out;
  const int* src = ei;              // edge_index[0]
  const int* dst = ei + N_EDGES;    // edge_index[1]

  char* p = (char*)d_ws;
  auto alloc = [&](size_t bytes) { char* r = p; p += (bytes + 255) & ~255ull; return r; };
  int*   degI   = (int*)alloc((size_t)N_NODES * 4);                           // 200192 B padded
  int*   start  = (int*)alloc((N_GRAPHS + 1) * 4);
  unsigned short* ell = (unsigned short*)alloc((size_t)N_NODES * MAXDEG * 2); // 6.4 MB
  unsigned int*   ellw= (unsigned int*)alloc((size_t)N_NODES * MAXDEG * 4);   // 12.8 MB
  unsigned short* T   = (unsigned short*)alloc((size_t)N_NODES * HID * 2);    // 12.8 MB
  unsigned short* T2  = (unsigned short*)alloc((size_t)N_NODES * HID * 2);    // 12.8 MB
  unsigned short* Hb  = (unsigned short*)alloc((size_t)N_NODES * HID * 2);    // 12.8 MB

  hipMemsetAsync(degI, 0, (size_t)N_NODES * 4, stream);

  int agg_blocks = (N_NODES / 2 * 64 + 255) / 256;   // 2 nodes per wave

  mega_kernel<<<GB0 + 55, 256, 0, stream>>>(src, dst, degI, ell,
                                            batch, start, x, W1, T);
  agg_gemm_kernel<<<AGB, 1024, 0, stream>>>((const unsigned int*)T, ell, degI,
                                            b1, W2, ellw, T2);
  aggregate_kernel<<<agg_blocks, 256, 0, stream>>>((const unsigned int*)T2, ellw, degI, b2,
                                                   (unsigned int*)Hb);
  pool_head_kernel<<<N_GRAPHS, 1024, 0, stream>>>((const unsigned int*)Hb, start,
                                                  Wfc, bfc, out);
}